// Round 14
// baseline (32057.672 us; speedup 1.0000x reference)
//
#include <hip/hip_runtime.h>

// Problem constants
#define IN_DIM 128
#define HID    512
#define BATCH  256
#define SEQT   512
#define G4H    2048
#define K0     640       // IN_DIM + HID (layer0 concat K)
#define K1     1024      // HID + HID   (layer1 concat K)
#define NC0    20        // K0/32
#define NC1    32        // K1/32
#define ROWB   2048      // bytes per A row (1024 bf16 cols)
#define FSTRIDE 32       // flag stride in dwords = 128B line per WG

typedef __attribute__((ext_vector_type(8))) short bf16x8;
typedef __attribute__((ext_vector_type(4))) float f32x4;

#define MFMA16 __builtin_amdgcn_mfma_f32_16x16x32_bf16
// glf layout [row 32][gate 4][col 32 +1 pad]
#define GL(r, g, c) ((r) * 132 + (g) * 33 + (c))

__device__ __forceinline__ unsigned short f2bf(float f) {  // RNE float->bf16
  unsigned u = __float_as_uint(f);
  u += 0x7fffu + ((u >> 16) & 1u);
  return (unsigned short)(u >> 16);
}
__device__ __forceinline__ float bf2f(unsigned short s) {
  return __uint_as_float(((unsigned)s) << 16);
}
__device__ __forceinline__ float sigm(float x) { return 1.0f / (1.0f + __expf(-x)); }
__device__ __forceinline__ float tanh_f(float x) {
  float xc = fminf(fmaxf(x, -15.0f), 15.0f);
  float e = __expf(2.0f * xc);
  return (e - 1.0f) / (e + 1.0f);
}

// ---------------------------------------------------------------------------
// Prep: packed hi/lo bf16 weight tiles + bias sums (layout unchanged).
// Tile t = slice16*4+gate; within tile: [kchunk][lane(col=l&15, ko=(l>>4)*8)][8].
// ---------------------------------------------------------------------------
__global__ void conv_weights(const float* __restrict__ Wih0, const float* __restrict__ Whh0,
                             const float* __restrict__ Wih1, const float* __restrict__ Whh1,
                             const float* __restrict__ bih0, const float* __restrict__ bhh0,
                             const float* __restrict__ bih1, const float* __restrict__ bhh1,
                             short* __restrict__ W0h, short* __restrict__ W0l,
                             short* __restrict__ W1h, short* __restrict__ W1l,
                             float* __restrict__ bsum0, float* __restrict__ bsum1) {
  int idx = blockIdx.x * blockDim.x + threadIdx.x;
  const int N0 = G4H * K0, N1 = G4H * K1;
  if (idx < N0) {
    int tile = idx / (K0 * 16), rem = idx % (K0 * 16);
    int kcg = rem >> 9, l = (rem >> 3) & 63, j = rem & 7;
    int slice = tile >> 2, g = tile & 3;
    int c = l & 15, k = kcg * 32 + ((l >> 4) << 3) + j;
    int n = g * HID + slice * 16 + c;
    float w = (k < IN_DIM) ? Wih0[n * IN_DIM + k] : Whh0[n * HID + (k - IN_DIM)];
    unsigned short hi = f2bf(w);
    W0h[idx] = (short)hi;
    W0l[idx] = (short)f2bf(w - bf2f(hi));
  } else if (idx < N0 + N1) {
    int d = idx - N0;
    int tile = d / (K1 * 16), rem = d % (K1 * 16);
    int kcg = rem >> 9, l = (rem >> 3) & 63, j = rem & 7;
    int slice = tile >> 2, g = tile & 3;
    int c = l & 15, k = kcg * 32 + ((l >> 4) << 3) + j;
    int n = g * HID + slice * 16 + c;
    float w = (k < HID) ? Wih1[n * HID + k] : Whh1[n * HID + (k - HID)];
    unsigned short hi = f2bf(w);
    W1h[d] = (short)hi;
    W1l[d] = (short)f2bf(w - bf2f(hi));
  } else if (idx < N0 + N1 + G4H) {
    int n = idx - (N0 + N1);
    bsum0[n] = bih0[n] + bhh0[n];
  } else if (idx < N0 + N1 + 2 * G4H) {
    int n = idx - (N0 + N1 + G4H);
    bsum1[n] = bih1[n] + bhh1[n];
  }
}

// ---------------------------------------------------------------------------
// Staging: packed h planes (dword = hi|lo<<16) -> swizzled hi/lo LDS planes.
// R14: PLAIN CACHED loads (no sc0 sc1). Coherence is provided by the
// release/acquire fence pair in group_barrier — same-XCD WGs now SHARE h
// lines in L2 instead of issuing 2.1M bypass transactions per step.
// ---------------------------------------------------------------------------
#define PKH(a, b) ((unsigned)((a) & 0xffffu) | (((b) & 0xffffu) << 16))
#define PKL(a, b) (((a) >> 16) | ((b) & 0xffff0000u))

__device__ __forceinline__ void unpack16(char* bh, char* bl, int byte0, int rx,
                                         const uint4& v0, const uint4& v1,
                                         const uint4& v2, const uint4& v3) {
  int4 h0 = {(int)PKH(v0.x, v0.y), (int)PKH(v0.z, v0.w), (int)PKH(v1.x, v1.y), (int)PKH(v1.z, v1.w)};
  int4 h1 = {(int)PKH(v2.x, v2.y), (int)PKH(v2.z, v2.w), (int)PKH(v3.x, v3.y), (int)PKH(v3.z, v3.w)};
  int4 l0 = {(int)PKL(v0.x, v0.y), (int)PKL(v0.z, v0.w), (int)PKL(v1.x, v1.y), (int)PKL(v1.z, v1.w)};
  int4 l1 = {(int)PKL(v2.x, v2.y), (int)PKL(v2.z, v2.w), (int)PKL(v3.x, v3.y), (int)PKL(v3.z, v3.w)};
  *(int4*)(bh + (byte0 ^ rx)) = h0;
  *(int4*)(bh + ((byte0 + 16) ^ rx)) = h1;
  *(int4*)(bl + (byte0 ^ rx)) = l0;
  *(int4*)(bl + ((byte0 + 16) ^ rx)) = l1;
}

// one plane (L0: h0p -> elems [128,640))
__device__ __forceinline__ void stage_one(char* AhiB, char* AloB,
                                          const unsigned* plane,
                                          int b0, int colOff, int tid) {
  const int row = tid >> 5, c32 = tid & 31;
  const uint4* p = (const uint4*)(plane + (size_t)(b0 + row) * HID + c32 * 16);
  uint4 v0 = p[0], v1 = p[1], v2 = p[2], v3 = p[3];
  const int rx = (row & 7) << 4;
  unpack16(AhiB + row * ROWB, AloB + row * ROWB, (colOff + c32 * 16) * 2, rx, v0, v1, v2, v3);
}

// two planes (L1: h0p -> [0,512), h2p -> [512,1024))
__device__ __forceinline__ void stage_two(char* AhiB, char* AloB,
                                          const unsigned* pA,
                                          const unsigned* pB,
                                          int b0, int tid) {
  const int row = tid >> 5, c32 = tid & 31;
  const uint4* p0 = (const uint4*)(pA + (size_t)(b0 + row) * HID + c32 * 16);
  const uint4* p2 = (const uint4*)(pB + (size_t)(b0 + row) * HID + c32 * 16);
  uint4 v0 = p0[0], v1 = p0[1], v2 = p0[2], v3 = p0[3];
  uint4 w0 = p2[0], w1 = p2[1], w2 = p2[2], w3 = p2[3];
  const int rx = (row & 7) << 4;
  char* bh = AhiB + row * ROWB;
  char* bl = AloB + row * ROWB;
  unpack16(bh, bl, (c32 * 16) * 2, rx, v0, v1, v2, v3);
  unpack16(bh, bl, (HID + c32 * 16) * 2, rx, w0, w1, w2, w3);
}
#undef PKH
#undef PKL

// ---------------------------------------------------------------------------
// Per-wave GEMM: 32 rows x 32 cols (2 N-tiles) over NKC k-chunks.
// Split precision: hi*hi + hi*lo + lo*hi  (12 MFMA / chunk).
// ---------------------------------------------------------------------------
template <int NKC>
__device__ __forceinline__ void gemm32(const char* Ah, const char* Al,
                                       const short* __restrict__ Bh0, const short* __restrict__ Bl0,
                                       const short* __restrict__ Bh1, const short* __restrict__ Bl1,
                                       int lane, int aoff,
                                       f32x4& a00, f32x4& a01, f32x4& a10, f32x4& a11) {
  const int row = lane & 15;
  const int ko  = (lane >> 4) * 8;
  const int rx  = (row & 7) << 4;
  const char* pAh0 = Ah + row * ROWB;
  const char* pAh1 = Ah + (row + 16) * ROWB;
  const char* pAl0 = Al + row * ROWB;
  const char* pAl1 = Al + (row + 16) * ROWB;
#pragma unroll
  for (int kc = 0; kc < NKC; ++kc) {
    const int off = ((aoff + kc * 32 + ko) * 2) ^ rx;
    bf16x8 ah0 = *(const bf16x8*)(pAh0 + off);
    bf16x8 ah1 = *(const bf16x8*)(pAh1 + off);
    bf16x8 al0 = *(const bf16x8*)(pAl0 + off);
    bf16x8 al1 = *(const bf16x8*)(pAl1 + off);
    bf16x8 bh0 = *(const bf16x8*)(Bh0 + kc * 512 + lane * 8);
    bf16x8 bl0 = *(const bf16x8*)(Bl0 + kc * 512 + lane * 8);
    bf16x8 bh1 = *(const bf16x8*)(Bh1 + kc * 512 + lane * 8);
    bf16x8 bl1 = *(const bf16x8*)(Bl1 + kc * 512 + lane * 8);
    a00 = MFMA16(ah0, bh0, a00, 0, 0, 0);
    a01 = MFMA16(ah1, bh0, a01, 0, 0, 0);
    a00 = MFMA16(ah0, bl0, a00, 0, 0, 0);
    a01 = MFMA16(ah1, bl0, a01, 0, 0, 0);
    a00 = MFMA16(al0, bh0, a00, 0, 0, 0);
    a01 = MFMA16(al1, bh0, a01, 0, 0, 0);
    a10 = MFMA16(ah0, bh1, a10, 0, 0, 0);
    a11 = MFMA16(ah1, bh1, a11, 0, 0, 0);
    a10 = MFMA16(ah0, bl1, a10, 0, 0, 0);
    a11 = MFMA16(ah1, bl1, a11, 0, 0, 0);
    a10 = MFMA16(al0, bh1, a10, 0, 0, 0);
    a11 = MFMA16(al1, bh1, a11, 0, 0, 0);
  }
}

__device__ __forceinline__ void finq32(float* glf, int g, int lane,
                                       const f32x4& a00, const f32x4& a01,
                                       const f32x4& a10, const f32x4& a11) {
  // C/D layout: col = lane&15, row = (lane>>4)*4 + reg  [measured m89]
  const int col = lane & 15;
  const int r0  = (lane >> 4) * 4;
#pragma unroll
  for (int r = 0; r < 4; ++r) {
    atomicAdd(glf + GL(r0 + r, g, col), a00[r]);       // ds_add_f32
    atomicAdd(glf + GL(16 + r0 + r, g, col), a01[r]);
    atomicAdd(glf + GL(r0 + r, g, col + 16), a10[r]);
    atomicAdd(glf + GL(16 + r0 + r, g, col + 16), a11[r]);
  }
}

// ---------------------------------------------------------------------------
// Release/acquire flag barrier (line-padded flags, no RMW).
// Producer: plain h stores (L2) -> release flag store (writes back dirty L2
// to MALL, then publishes). Consumer: relaxed poll -> acquire fence
// (invalidates stale L1/L2) -> plain h loads hit fresh lines, shared in L2.
// ---------------------------------------------------------------------------
__device__ __forceinline__ void group_barrier(unsigned* flags, unsigned target,
                                              int tid, int wid) {
  __syncthreads();                 // all WG h-stores retired before release
  if (tid == 0)
    __hip_atomic_store(flags + wid * FSTRIDE, target,
                       __ATOMIC_RELEASE, __HIP_MEMORY_SCOPE_AGENT);
  if (tid < 64) {
    const int i = (tid & 31) * FSTRIDE;
    while (true) {
      unsigned v = __hip_atomic_load(flags + i, __ATOMIC_RELAXED,
                                     __HIP_MEMORY_SCOPE_AGENT);
      if (__all((int)(v >= target))) break;
      __builtin_amdgcn_s_sleep(1);
    }
  }
  __syncthreads();
  __builtin_amdgcn_fence(__ATOMIC_ACQUIRE, "agent");   // inv stale h lines
}

// ---------------------------------------------------------------------------
// Persistent fused 2-layer LSTM, layer-split across WGs (R9/R13 structure).
// 256 WGs x 1024 thr. grp = blk>>5 (32 batch rows). Within a group:
//   WGs 0-15  = layer 0, 32 hid cols each (reads x_t + h0p, writes h0c)
//   WGs 16-31 = layer 1, one step behind  (reads h0p + h2p, writes h2c)
// Wave w: gate g = w&3, K-quarter kq = w>>2; gate partials via LDS atomicAdd.
// Per step: stage -> sync -> gemm -> sync -> update+store -> fence barrier.
// ---------------------------------------------------------------------------
__global__ void __launch_bounds__(1024, 4) lstm_fused(
    const float* __restrict__ x,
    const float* __restrict__ Wfc, const float* __restrict__ bfc,
    const short* __restrict__ W0h, const short* __restrict__ W0l,
    const short* __restrict__ W1h, const short* __restrict__ W1l,
    const float* __restrict__ bsum0, const float* __restrict__ bsum1,
    unsigned* h0s, unsigned* h2s,
    unsigned* counters,
    float* __restrict__ out) {
  const int tid  = threadIdx.x;
  const int wv   = tid >> 6;
  const int lane = tid & 63;
  const int wid  = blockIdx.x & 31;
  const int grp  = blockIdx.x >> 5;
  const int role = wid >> 4;           // 0 = layer0, 1 = layer1
  const int w16  = wid & 15;           // 16 col-slices of 32
  const int hid0 = w16 * 32;
  const int b0   = grp * 32;
  unsigned* flags = counters + grp * (32 * FSTRIDE);   // 4KB per group

  __shared__ __align__(16) char AhiB[32 * ROWB];   // 65536 B
  __shared__ __align__(16) char AloB[32 * ROWB];   // 65536 B
  __shared__ float glf[32 * 132];                   // 16896 B gate exchange / FC scratch

  const int g  = wv & 3;
  const int kq = wv >> 2;
  // Weight tile pointers: 16-col tiles t0,t1 for this wave's 32 cols.
  const int t0 = (w16 * 2) * 4 + g, t1 = t0 + 4;
  const short *Bh0, *Bl0, *Bh1, *Bl1;
  int aoff;
  if (role == 0) {
    Bh0 = W0h + ((size_t)t0 * NC0 + (size_t)kq * 5) * 512;
    Bl0 = W0l + ((size_t)t0 * NC0 + (size_t)kq * 5) * 512;
    Bh1 = W0h + ((size_t)t1 * NC0 + (size_t)kq * 5) * 512;
    Bl1 = W0l + ((size_t)t1 * NC0 + (size_t)kq * 5) * 512;
    aoff = kq * 160;
  } else {
    Bh0 = W1h + ((size_t)t0 * NC1 + (size_t)kq * 8) * 512;
    Bl0 = W1l + ((size_t)t0 * NC1 + (size_t)kq * 8) * 512;
    Bh1 = W1h + ((size_t)t1 * NC1 + (size_t)kq * 8) * 512;
    Bl1 = W1l + ((size_t)t1 * NC1 + (size_t)kq * 8) * 512;
    aoff = kq * 256;
  }

  // Cell state + biases: 1 output/thread (row = tid>>5, col = tid&31)
  float c = 0.f;
  float bs[4];
  {
    const int n = hid0 + (tid & 31);
    const float* bsp = role ? bsum1 : bsum0;
#pragma unroll
    for (int q = 0; q < 4; ++q) bs[q] = bsp[q * HID + n];
  }
  for (int i = tid; i < 32 * 132; i += 1024) glf[i] = 0.f;

  const size_t PL = (size_t)BATCH * HID;

  for (int s = 0; s <= SEQT; ++s) {
    const int cur = s & 1, prv = cur ^ 1;
    unsigned* h0c = h0s + (size_t)cur * PL;
    const unsigned* h0p = h0s + (size_t)prv * PL;
    unsigned* h2c = h2s + (size_t)cur * PL;
    const unsigned* h2p = h2s + (size_t)prv * PL;
    const bool active = role ? (s > 0) : (s < SEQT);

    // ---- stage (plain cached loads; fresh by acquire fence) ----
    if (active) {
      if (role == 0) {
        {  // x_t -> elems [0,128) hi/lo
          const int row = tid >> 5, t32 = tid & 31;
          const int rx = (row & 7) << 4;
          const float* xs = x + ((size_t)(b0 + row) * SEQT + s) * IN_DIM + t32 * 4;
          float4 xv = *(const float4*)xs;
          unsigned short h0v = f2bf(xv.x), h1v = f2bf(xv.y), h2v = f2bf(xv.z), h3v = f2bf(xv.w);
          uint2 hd = {(unsigned)h0v | ((unsigned)h1v << 16), (unsigned)h2v | ((unsigned)h3v << 16)};
          uint2 ld = {(unsigned)f2bf(xv.x - bf2f(h0v)) | ((unsigned)f2bf(xv.y - bf2f(h1v)) << 16),
                      (unsigned)f2bf(xv.z - bf2f(h2v)) | ((unsigned)f2bf(xv.w - bf2f(h3v)) << 16)};
          const int byte = (t32 * 8) ^ rx;
          *(uint2*)(AhiB + row * ROWB + byte) = hd;
          *(uint2*)(AloB + row * ROWB + byte) = ld;
        }
        stage_one(AhiB, AloB, h0p, b0, IN_DIM, tid);     // h0p -> [128,640)
      } else {
        stage_two(AhiB, AloB, h0p, h2p, b0, tid);        // h0p->[0,512), h2p->[512,1024)
      }
    }
    __syncthreads();

    // ---- gemm + gate reduce ----
    if (active) {
      f32x4 a00 = {0.f, 0.f, 0.f, 0.f}, a01 = {0.f, 0.f, 0.f, 0.f};
      f32x4 a10 = {0.f, 0.f, 0.f, 0.f}, a11 = {0.f, 0.f, 0.f, 0.f};
      if (role == 0)
        gemm32<5>(AhiB, AloB, Bh0, Bl0, Bh1, Bl1, lane, aoff, a00, a01, a10, a11);
      else
        gemm32<8>(AhiB, AloB, Bh0, Bl0, Bh1, Bl1, lane, aoff, a00, a01, a10, a11);
      finq32(glf, g, lane, a00, a01, a10, a11);
    }
    __syncthreads();

    // ---- update + plain h store (released by the barrier) ----
    if (active) {
      const int row = tid >> 5, col = tid & 31;
      float gi = glf[GL(row, 0, col)] + bs[0];
      float gf = glf[GL(row, 1, col)] + bs[1];
      float gg = glf[GL(row, 2, col)] + bs[2];
      float go = glf[GL(row, 3, col)] + bs[3];
      glf[GL(row, 0, col)] = 0.f; glf[GL(row, 1, col)] = 0.f;
      glf[GL(row, 2, col)] = 0.f; glf[GL(row, 3, col)] = 0.f;
      float i = sigm(gi), f = sigm(gf), gv = tanh_f(gg), o = sigm(go);
      float cc = f * c + i * gv;
      c = cc;
      float h = o * tanh_f(cc);
      unsigned short hh = f2bf(h);
      unsigned short hl = f2bf(h - bf2f(hh));
      unsigned pk = (unsigned)hh | ((unsigned)hl << 16);
      unsigned* hc = role ? h2c : h0c;
      hc[(size_t)(b0 + row) * HID + hid0 + col] = pk;
    }

    group_barrier(flags, (unsigned)(s + 1), tid, wid);
  }

  // ---- FC epilogue: WG 0 of each group (h2 final in buf 0) ----
  {
    const int p = tid >> 3, q = tid & 7;   // 64 (row,out) pairs x 8 K-eighths
    float acc = 0.f;
    if (wid == 0 && tid < 512) {
      const int b = b0 + (p >> 1), o = p & 1;
      const unsigned* sp = h2s + (size_t)b * HID + q * 64;
      const float* wf = Wfc + (size_t)o * HID + q * 64;
#pragma unroll 8
      for (int i = 0; i < 64; ++i) {
        unsigned u = sp[i];
        acc += (bf2f((unsigned short)(u & 0xffff)) + bf2f((unsigned short)(u >> 16))) * wf[i];
      }
      glf[p * 8 + q] = acc;
    }
    __syncthreads();
    if (wid == 0 && tid < 512 && q == 0) {
      float t = 0.f;
#pragma unroll
      for (int i = 0; i < 8; ++i) t += glf[p * 8 + i];
      out[(b0 + (p >> 1)) * 2 + (p & 1)] = t + bfc[p & 1];
    }
  }
}

// ---------------------------------------------------------------------------
extern "C" void kernel_launch(void* const* d_in, const int* in_sizes, int n_in,
                              void* d_out, int out_size, void* d_ws, size_t ws_size,
                              hipStream_t stream) {
  const float* x    = (const float*)d_in[0];
  const float* Wih0 = (const float*)d_in[1];
  const float* Whh0 = (const float*)d_in[2];
  const float* bih0 = (const float*)d_in[3];
  const float* bhh0 = (const float*)d_in[4];
  const float* Wih1 = (const float*)d_in[5];
  const float* Whh1 = (const float*)d_in[6];
  const float* bih1 = (const float*)d_in[7];
  const float* bhh1 = (const float*)d_in[8];
  const float* Wfc  = (const float*)d_in[9];
  const float* bfc  = (const float*)d_in[10];
  float* out = (float*)d_out;

  // Workspace layout (~15.8 MB)
  short* W0h = (short*)d_ws;
  short* W0l = W0h + (size_t)G4H * K0;
  short* W1h = W0l + (size_t)G4H * K0;
  short* W1l = W1h + (size_t)G4H * K1;
  unsigned* h0s = (unsigned*)(W1l + (size_t)G4H * K1);   // [2 buf][BATCH][HID] packed
  unsigned* h2s = h0s + (size_t)2 * BATCH * HID;
  unsigned* counters = h2s + (size_t)2 * BATCH * HID;     // 8 groups x 32 x FSTRIDE dw
  float* bsum0 = (float*)(counters + 8 * 32 * FSTRIDE);
  float* bsum1 = bsum0 + G4H;

  // Zero h double-buffers + padded flags (every launch: graph-replay safe)
  (void)hipMemsetAsync(h0s, 0,
                       (size_t)4 * BATCH * HID * sizeof(unsigned) +
                           (size_t)8 * 32 * FSTRIDE * sizeof(unsigned),
                       stream);

  const int total = G4H * K0 + G4H * K1 + 2 * G4H;
  conv_weights<<<(total + 255) / 256, 256, 0, stream>>>(
      Wih0, Whh0, Wih1, Whh1, bih0, bhh0, bih1, bhh1,
      W0h, W0l, W1h, W1l, bsum0, bsum1);

  void* args[] = {(void*)&x,    (void*)&Wfc,  (void*)&bfc,
                  (void*)&W0h,  (void*)&W0l,  (void*)&W1h, (void*)&W1l,
                  (void*)&bsum0, (void*)&bsum1,
                  (void*)&h0s,  (void*)&h2s,  (void*)&counters, (void*)&out};
  (void)hipLaunchCooperativeKernel((void*)lstm_fused, dim3(256), dim3(1024), args, 0,
                                   stream);
}

// Round 15
// 14526.443 us; speedup vs baseline: 2.2068x; 2.2068x over previous
//
#include <hip/hip_runtime.h>

// Problem constants
#define IN_DIM 128
#define HID    512
#define BATCH  256
#define SEQT   512
#define G4H    2048
#define K0     640       // IN_DIM + HID (layer0 concat K)
#define K1     1024      // HID + HID   (layer1 concat K)
#define NC0    20        // K0/32
#define NC1    32        // K1/32
#define ROWB   2048      // bytes per A row (1024 bf16 cols)
#define FSTRIDE 32       // flag stride in dwords = 128B line per WG

typedef __attribute__((ext_vector_type(8))) short bf16x8;
typedef __attribute__((ext_vector_type(4))) float f32x4;

#define MFMA16 __builtin_amdgcn_mfma_f32_16x16x32_bf16
// glf layout [row 32][gate 4][col 32 +1 pad]
#define GL(r, g, c) ((r) * 132 + (g) * 33 + (c))

__device__ __forceinline__ unsigned short f2bf(float f) {  // RNE float->bf16
  unsigned u = __float_as_uint(f);
  u += 0x7fffu + ((u >> 16) & 1u);
  return (unsigned short)(u >> 16);
}
__device__ __forceinline__ float bf2f(unsigned short s) {
  return __uint_as_float(((unsigned)s) << 16);
}
__device__ __forceinline__ float sigm(float x) { return 1.0f / (1.0f + __expf(-x)); }
__device__ __forceinline__ float tanh_f(float x) {
  float xc = fminf(fmaxf(x, -15.0f), 15.0f);
  float e = __expf(2.0f * xc);
  return (e - 1.0f) / (e + 1.0f);
}

// MALL-coherent dword load (agent scope)
__device__ __forceinline__ unsigned ald(const unsigned* p) {
  return __hip_atomic_load(p, __ATOMIC_RELAXED, __HIP_MEMORY_SCOPE_AGENT);
}

// ---------------------------------------------------------------------------
// Prep: packed hi/lo bf16 weight tiles + bias sums (unchanged layout).
// Tile t = slice16*4+gate; within tile: [kchunk][lane(col=l&15, ko=(l>>4)*8)][8].
// ---------------------------------------------------------------------------
__global__ void conv_weights(const float* __restrict__ Wih0, const float* __restrict__ Whh0,
                             const float* __restrict__ Wih1, const float* __restrict__ Whh1,
                             const float* __restrict__ bih0, const float* __restrict__ bhh0,
                             const float* __restrict__ bih1, const float* __restrict__ bhh1,
                             short* __restrict__ W0h, short* __restrict__ W0l,
                             short* __restrict__ W1h, short* __restrict__ W1l,
                             float* __restrict__ bsum0, float* __restrict__ bsum1) {
  int idx = blockIdx.x * blockDim.x + threadIdx.x;
  const int N0 = G4H * K0, N1 = G4H * K1;
  if (idx < N0) {
    int tile = idx / (K0 * 16), rem = idx % (K0 * 16);
    int kcg = rem >> 9, l = (rem >> 3) & 63, j = rem & 7;
    int slice = tile >> 2, g = tile & 3;
    int c = l & 15, k = kcg * 32 + ((l >> 4) << 3) + j;
    int n = g * HID + slice * 16 + c;
    float w = (k < IN_DIM) ? Wih0[n * IN_DIM + k] : Whh0[n * HID + (k - IN_DIM)];
    unsigned short hi = f2bf(w);
    W0h[idx] = (short)hi;
    W0l[idx] = (short)f2bf(w - bf2f(hi));
  } else if (idx < N0 + N1) {
    int d = idx - N0;
    int tile = d / (K1 * 16), rem = d % (K1 * 16);
    int kcg = rem >> 9, l = (rem >> 3) & 63, j = rem & 7;
    int slice = tile >> 2, g = tile & 3;
    int c = l & 15, k = kcg * 32 + ((l >> 4) << 3) + j;
    int n = g * HID + slice * 16 + c;
    float w = (k < HID) ? Wih1[n * HID + k] : Whh1[n * HID + (k - HID)];
    unsigned short hi = f2bf(w);
    W1h[d] = (short)hi;
    W1l[d] = (short)f2bf(w - bf2f(hi));
  } else if (idx < N0 + N1 + G4H) {
    int n = idx - (N0 + N1);
    bsum0[n] = bih0[n] + bhh0[n];
  } else if (idx < N0 + N1 + 2 * G4H) {
    int n = idx - (N0 + N1 + G4H);
    bsum1[n] = bih1[n] + bhh1[n];
  }
}

// ---------------------------------------------------------------------------
// Staging. h is SINGLE-PLANE bf16 (ushort/element) — R15 change: halves the
// bypass transaction count vs packed hi|lo dwords. Raw ushorts go straight
// into the LDS A plane (no unpacking). x keeps hi+lo (f32 source, plain
// cached loads; lo parked in unused cols [640,768) of the same plane).
// ---------------------------------------------------------------------------

// L0: x -> cols [0,128) hi + [640,768) lo; h0p(ushort, bypass) -> cols [128,640)
__device__ __forceinline__ void stage_l0(char* Ah, const float* __restrict__ x,
                                         const unsigned short* __restrict__ h0p,
                                         int b0, int s, int tid) {
  const int row = tid >> 5, c32 = tid & 31;
  const int rx = (row & 7) << 4;
  char* base = Ah + row * ROWB;
  {  // x: 4 floats -> 4 hi ushorts + 4 lo ushorts
    const float* xs = x + ((size_t)(b0 + row) * SEQT + s) * IN_DIM + c32 * 4;
    float4 xv = *(const float4*)xs;
    unsigned short h0 = f2bf(xv.x), h1 = f2bf(xv.y), h2 = f2bf(xv.z), h3 = f2bf(xv.w);
    uint2 hd = {(unsigned)h0 | ((unsigned)h1 << 16), (unsigned)h2 | ((unsigned)h3 << 16)};
    uint2 ld = {(unsigned)f2bf(xv.x - bf2f(h0)) | ((unsigned)f2bf(xv.y - bf2f(h1)) << 16),
                (unsigned)f2bf(xv.z - bf2f(h2)) | ((unsigned)f2bf(xv.w - bf2f(h3)) << 16)};
    *(uint2*)(base + ((c32 * 8) ^ rx)) = hd;               // hi at col c32*4
    *(uint2*)(base + ((1280 + c32 * 8) ^ rx)) = ld;        // lo at col 640 + c32*4
  }
  {  // h: 16 ushorts (32B) via 2 bypass dwordx4
    const unsigned short* hp = h0p + (size_t)(b0 + row) * HID + c32 * 16;
    uint4 v0, v1;
    asm volatile(
        "global_load_dwordx4 %0, %2, off sc0 sc1\n\t"
        "global_load_dwordx4 %1, %2, off offset:16 sc0 sc1\n\t"
        "s_waitcnt vmcnt(0)"
        : "=&v"(v0), "=&v"(v1) : "v"(hp) : "memory");
    const int byte0 = 256 + c32 * 32;                      // col 128 + c32*16
    *(int4*)(base + (byte0 ^ rx)) = *(int4*)&v0;
    *(int4*)(base + ((byte0 + 16) ^ rx)) = *(int4*)&v1;
  }
}

// L1: h0p -> cols [0,512), h2p -> cols [512,1024); 4 bypass dwordx4 per thread
__device__ __forceinline__ void stage_l1(char* Ah,
                                         const unsigned short* __restrict__ h0p,
                                         const unsigned short* __restrict__ h2p,
                                         int b0, int tid) {
  const int row = tid >> 5, c32 = tid & 31;
  const int rx = (row & 7) << 4;
  char* base = Ah + row * ROWB;
  const unsigned short* p0 = h0p + (size_t)(b0 + row) * HID + c32 * 16;
  const unsigned short* p2 = h2p + (size_t)(b0 + row) * HID + c32 * 16;
  uint4 v0, v1, w0, w1;
  asm volatile(
      "global_load_dwordx4 %0, %4, off sc0 sc1\n\t"
      "global_load_dwordx4 %1, %4, off offset:16 sc0 sc1\n\t"
      "global_load_dwordx4 %2, %5, off sc0 sc1\n\t"
      "global_load_dwordx4 %3, %5, off offset:16 sc0 sc1\n\t"
      "s_waitcnt vmcnt(0)"
      : "=&v"(v0), "=&v"(v1), "=&v"(w0), "=&v"(w1)
      : "v"(p0), "v"(p2) : "memory");
  const int b0b = c32 * 32;            // col c32*16
  *(int4*)(base + (b0b ^ rx)) = *(int4*)&v0;
  *(int4*)(base + ((b0b + 16) ^ rx)) = *(int4*)&v1;
  const int b2b = 1024 + c32 * 32;     // col 512 + c32*16
  *(int4*)(base + (b2b ^ rx)) = *(int4*)&w0;
  *(int4*)(base + ((b2b + 16) ^ rx)) = *(int4*)&w1;
}

// ---------------------------------------------------------------------------
// Per-wave GEMMs: 32 rows x 32 cols (2 N-tiles). Weights stay hi+lo split;
// A is single-plane bf16 except x cols (lo at col 640+k). 8 MFMA per h-chunk,
// 12 per x-chunk.
// ---------------------------------------------------------------------------
template <int NKC>
__device__ __forceinline__ void gemm_seq(const char* Ah, bool xlo,
                                         const short* __restrict__ Bh0, const short* __restrict__ Bl0,
                                         const short* __restrict__ Bh1, const short* __restrict__ Bl1,
                                         int lane, int aoff,
                                         f32x4& a00, f32x4& a01, f32x4& a10, f32x4& a11) {
  const int row = lane & 15;
  const int ko  = (lane >> 4) * 8;
  const int rx  = (row & 7) << 4;
  const char* pA0 = Ah + row * ROWB;
  const char* pA1 = Ah + (row + 16) * ROWB;
#pragma unroll
  for (int kc = 0; kc < NKC; ++kc) {
    const int k = aoff + kc * 32;
    const int off = ((k + ko) * 2) ^ rx;
    bf16x8 ah0 = *(const bf16x8*)(pA0 + off);
    bf16x8 ah1 = *(const bf16x8*)(pA1 + off);
    bf16x8 bh0 = *(const bf16x8*)(Bh0 + kc * 512 + lane * 8);
    bf16x8 bl0 = *(const bf16x8*)(Bl0 + kc * 512 + lane * 8);
    bf16x8 bh1 = *(const bf16x8*)(Bh1 + kc * 512 + lane * 8);
    bf16x8 bl1 = *(const bf16x8*)(Bl1 + kc * 512 + lane * 8);
    a00 = MFMA16(ah0, bh0, a00, 0, 0, 0);
    a01 = MFMA16(ah1, bh0, a01, 0, 0, 0);
    a00 = MFMA16(ah0, bl0, a00, 0, 0, 0);
    a01 = MFMA16(ah1, bl0, a01, 0, 0, 0);
    a10 = MFMA16(ah0, bh1, a10, 0, 0, 0);
    a11 = MFMA16(ah1, bh1, a11, 0, 0, 0);
    a10 = MFMA16(ah0, bl1, a10, 0, 0, 0);
    a11 = MFMA16(ah1, bl1, a11, 0, 0, 0);
    if (xlo && k < IN_DIM) {   // x columns carry an A-lo plane at col 640+k
      const int offl = ((1280 + (k + ko) * 2)) ^ rx;
      bf16x8 al0 = *(const bf16x8*)(pA0 + offl);
      bf16x8 al1 = *(const bf16x8*)(pA1 + offl);
      a00 = MFMA16(al0, bh0, a00, 0, 0, 0);
      a01 = MFMA16(al1, bh0, a01, 0, 0, 0);
      a10 = MFMA16(al0, bh1, a10, 0, 0, 0);
      a11 = MFMA16(al1, bh1, a11, 0, 0, 0);
    }
  }
}

__device__ __forceinline__ void finq32(float* glf, int g, int lane,
                                       const f32x4& a00, const f32x4& a01,
                                       const f32x4& a10, const f32x4& a11) {
  // C/D layout: col = lane&15, row = (lane>>4)*4 + reg  [measured m89]
  const int col = lane & 15;
  const int r0  = (lane >> 4) * 4;
#pragma unroll
  for (int r = 0; r < 4; ++r) {
    atomicAdd(glf + GL(r0 + r, g, col), a00[r]);       // ds_add_f32
    atomicAdd(glf + GL(16 + r0 + r, g, col), a01[r]);
    atomicAdd(glf + GL(r0 + r, g, col + 16), a10[r]);
    atomicAdd(glf + GL(16 + r0 + r, g, col + 16), a11[r]);
  }
}

// ---------------------------------------------------------------------------
// Flag-array group barrier, one 128B line per WG (R13, proven stable).
// ---------------------------------------------------------------------------
__device__ __forceinline__ void group_barrier(unsigned* flags, unsigned target,
                                              int tid, int wid) {
  asm volatile("s_waitcnt vmcnt(0)" ::: "memory");   // all this thread's stores acked
  __syncthreads();                                   // whole WG arrived
  if (tid < 64) {
    if (tid == 0)
      __hip_atomic_store(flags + wid * FSTRIDE, target,
                         __ATOMIC_RELAXED, __HIP_MEMORY_SCOPE_AGENT);
    const int i = (tid & 31) * FSTRIDE;
    while (true) {
      unsigned v = ald(flags + i);
      if (__all((int)(v >= target))) break;
      __builtin_amdgcn_s_sleep(1);
    }
  }
  __syncthreads();
}

// ---------------------------------------------------------------------------
// Persistent fused 2-layer LSTM, layer-split across WGs (R13 structure).
// 256 WGs x 1024 thr. grp = blk>>5 (32 batch rows). Within a group:
//   WGs 0-15  = layer 0, 32 hid cols each (reads x_t + h0p, writes h0c)
//   WGs 16-31 = layer 1, one step behind  (reads h0p + h2p, writes h2c)
// h exchanged as SINGLE bf16 ushort per element (R15).
// ---------------------------------------------------------------------------
__global__ void __launch_bounds__(1024, 4) lstm_fused(
    const float* __restrict__ x,
    const float* __restrict__ Wfc, const float* __restrict__ bfc,
    const short* __restrict__ W0h, const short* __restrict__ W0l,
    const short* __restrict__ W1h, const short* __restrict__ W1l,
    const float* __restrict__ bsum0, const float* __restrict__ bsum1,
    unsigned short* __restrict__ h0s, unsigned short* __restrict__ h2s,
    unsigned* __restrict__ counters,
    float* __restrict__ out) {
  const int tid  = threadIdx.x;
  const int wv   = tid >> 6;
  const int lane = tid & 63;
  const int wid  = blockIdx.x & 31;
  const int grp  = blockIdx.x >> 5;
  const int role = wid >> 4;           // 0 = layer0, 1 = layer1
  const int w16  = wid & 15;           // 16 col-slices of 32
  const int hid0 = w16 * 32;
  const int b0   = grp * 32;
  unsigned* flags = counters + grp * (32 * FSTRIDE);   // 4KB per group

  __shared__ __align__(16) char AhB[32 * ROWB];    // 65536 B single A plane
  __shared__ float glf[32 * 132];                   // 16896 B gate exchange / FC scratch

  const int g  = wv & 3;
  const int kq = wv >> 2;
  const int t0 = (w16 * 2) * 4 + g, t1 = t0 + 4;
  const short *Bh0, *Bl0, *Bh1, *Bl1;
  int aoff;
  if (role == 0) {
    Bh0 = W0h + ((size_t)t0 * NC0 + (size_t)kq * 5) * 512;
    Bl0 = W0l + ((size_t)t0 * NC0 + (size_t)kq * 5) * 512;
    Bh1 = W0h + ((size_t)t1 * NC0 + (size_t)kq * 5) * 512;
    Bl1 = W0l + ((size_t)t1 * NC0 + (size_t)kq * 5) * 512;
    aoff = kq * 160;
  } else {
    Bh0 = W1h + ((size_t)t0 * NC1 + (size_t)kq * 8) * 512;
    Bl0 = W1l + ((size_t)t0 * NC1 + (size_t)kq * 8) * 512;
    Bh1 = W1h + ((size_t)t1 * NC1 + (size_t)kq * 8) * 512;
    Bl1 = W1l + ((size_t)t1 * NC1 + (size_t)kq * 8) * 512;
    aoff = kq * 256;
  }

  // Cell state + biases: 1 output/thread (row = tid>>5, col = tid&31)
  float c = 0.f;
  float bs[4];
  {
    const int n = hid0 + (tid & 31);
    const float* bsp = role ? bsum1 : bsum0;
#pragma unroll
    for (int q = 0; q < 4; ++q) bs[q] = bsp[q * HID + n];
  }
  for (int i = tid; i < 32 * 132; i += 1024) glf[i] = 0.f;

  const size_t PL = (size_t)BATCH * HID;

  for (int s = 0; s <= SEQT; ++s) {
    const int cur = s & 1, prv = cur ^ 1;
    unsigned short* h0c = h0s + (size_t)cur * PL;
    const unsigned short* h0p = h0s + (size_t)prv * PL;
    unsigned short* h2c = h2s + (size_t)cur * PL;
    const unsigned short* h2p = h2s + (size_t)prv * PL;
    const bool active = role ? (s > 0) : (s < SEQT);

    // ---- stage ----
    if (active) {
      if (role == 0) stage_l0(AhB, x, h0p, b0, s, tid);
      else           stage_l1(AhB, h0p, h2p, b0, tid);
    }
    __syncthreads();

    // ---- gemm + gate reduce ----
    if (active) {
      f32x4 a00 = {0.f, 0.f, 0.f, 0.f}, a01 = {0.f, 0.f, 0.f, 0.f};
      f32x4 a10 = {0.f, 0.f, 0.f, 0.f}, a11 = {0.f, 0.f, 0.f, 0.f};
      if (role == 0)
        gemm_seq<5>(AhB, true, Bh0, Bl0, Bh1, Bl1, lane, aoff, a00, a01, a10, a11);
      else
        gemm_seq<8>(AhB, false, Bh0, Bl0, Bh1, Bl1, lane, aoff, a00, a01, a10, a11);
      finq32(glf, g, lane, a00, a01, a10, a11);
    }
    __syncthreads();

    // ---- update + bf16 h store (bypass) ----
    if (active) {
      const int row = tid >> 5, col = tid & 31;
      float gi = glf[GL(row, 0, col)] + bs[0];
      float gf = glf[GL(row, 1, col)] + bs[1];
      float gg = glf[GL(row, 2, col)] + bs[2];
      float go = glf[GL(row, 3, col)] + bs[3];
      glf[GL(row, 0, col)] = 0.f; glf[GL(row, 1, col)] = 0.f;
      glf[GL(row, 2, col)] = 0.f; glf[GL(row, 3, col)] = 0.f;
      float i = sigm(gi), f = sigm(gf), gv = tanh_f(gg), o = sigm(go);
      float cc = f * c + i * gv;
      c = cc;
      float h = o * tanh_f(cc);
      unsigned short hv = f2bf(h);
      unsigned short* hc = role ? h2c : h0c;
      __hip_atomic_store(hc + (size_t)(b0 + row) * HID + hid0 + col, hv,
                         __ATOMIC_RELAXED, __HIP_MEMORY_SCOPE_AGENT);
    }

    group_barrier(flags, (unsigned)(s + 1), tid, wid);
  }

  // ---- FC epilogue: WG 0 of each group (h2 final in buf 0) ----
  {
    const int p = tid >> 3, q = tid & 7;   // 64 (row,out) pairs x 8 K-eighths
    float acc = 0.f;
    if (wid == 0 && tid < 512) {
      const int b = b0 + (p >> 1), o = p & 1;
      const unsigned* sp = (const unsigned*)(h2s + (size_t)b * HID) + q * 32;
      const float* wf = Wfc + (size_t)o * HID + q * 64;
#pragma unroll 8
      for (int i = 0; i < 32; ++i) {
        unsigned u = ald(sp + i);
        acc += bf2f((unsigned short)(u & 0xffff)) * wf[2 * i] +
               bf2f((unsigned short)(u >> 16)) * wf[2 * i + 1];
      }
      glf[p * 8 + q] = acc;
    }
    __syncthreads();
    if (wid == 0 && tid < 512 && q == 0) {
      float t = 0.f;
#pragma unroll
      for (int i = 0; i < 8; ++i) t += glf[p * 8 + i];
      out[(b0 + (p >> 1)) * 2 + (p & 1)] = t + bfc[p & 1];
    }
  }
}

// ---------------------------------------------------------------------------
extern "C" void kernel_launch(void* const* d_in, const int* in_sizes, int n_in,
                              void* d_out, int out_size, void* d_ws, size_t ws_size,
                              hipStream_t stream) {
  const float* x    = (const float*)d_in[0];
  const float* Wih0 = (const float*)d_in[1];
  const float* Whh0 = (const float*)d_in[2];
  const float* bih0 = (const float*)d_in[3];
  const float* bhh0 = (const float*)d_in[4];
  const float* Wih1 = (const float*)d_in[5];
  const float* Whh1 = (const float*)d_in[6];
  const float* bih1 = (const float*)d_in[7];
  const float* bhh1 = (const float*)d_in[8];
  const float* Wfc  = (const float*)d_in[9];
  const float* bfc  = (const float*)d_in[10];
  float* out = (float*)d_out;

  // Workspace layout (~15 MB)
  short* W0h = (short*)d_ws;
  short* W0l = W0h + (size_t)G4H * K0;
  short* W1h = W0l + (size_t)G4H * K0;
  short* W1l = W1h + (size_t)G4H * K1;
  unsigned short* h0s = (unsigned short*)(W1l + (size_t)G4H * K1);  // [2][BATCH][HID] bf16
  unsigned short* h2s = h0s + (size_t)2 * BATCH * HID;
  unsigned* counters = (unsigned*)(h2s + (size_t)2 * BATCH * HID);  // 8 x 32 x FSTRIDE dw
  float* bsum0 = (float*)(counters + 8 * 32 * FSTRIDE);
  float* bsum1 = bsum0 + G4H;

  // Zero h double-buffers + padded flags (every launch: graph-replay safe)
  (void)hipMemsetAsync(h0s, 0,
                       (size_t)4 * BATCH * HID * sizeof(unsigned short) +
                           (size_t)8 * 32 * FSTRIDE * sizeof(unsigned),
                       stream);

  const int total = G4H * K0 + G4H * K1 + 2 * G4H;
  conv_weights<<<(total + 255) / 256, 256, 0, stream>>>(
      Wih0, Whh0, Wih1, Whh1, bih0, bhh0, bih1, bhh1,
      W0h, W0l, W1h, W1l, bsum0, bsum1);

  void* args[] = {(void*)&x,    (void*)&Wfc,  (void*)&bfc,
                  (void*)&W0h,  (void*)&W0l,  (void*)&W1h, (void*)&W1l,
                  (void*)&bsum0, (void*)&bsum1,
                  (void*)&h0s,  (void*)&h2s,  (void*)&counters, (void*)&out};
  (void)hipLaunchCooperativeKernel((void*)lstm_fused, dim3(256), dim3(1024), args, 0,
                                   stream);
}